// Round 3
// baseline (162.141 us; speedup 1.0000x reference)
//
#include <hip/hip_runtime.h>
#include <math.h>

#define ROWLEN 16384
#define BLOCK  512
#define NCHUNK 8              // 8 x float4 = 32 floats / thread; 512*32 = 16384
#define NMOM   9              // central moments p = 2..10
#define EPSV   1e-10

__global__ __launch_bounds__(BLOCK) void moments_kernel(
    const float* __restrict__ y, float* __restrict__ out)
{
    const int row  = blockIdx.x;
    const int tid  = threadIdx.x;
    const int wave = tid >> 6;
    const int lane = tid & 63;

    const float4* yrow = reinterpret_cast<const float4*>(y + (size_t)row * ROWLEN);

    // ---- single HBM read: keep the whole row in registers ----
    float4 v[NCHUNK];
#pragma unroll
    for (int i = 0; i < NCHUNK; ++i)
        v[i] = yrow[i * BLOCK + tid];

    // ---- phase 1: mean ----
    double tsum = 0.0;
#pragma unroll
    for (int i = 0; i < NCHUNK; ++i) {
        float s = (v[i].x + v[i].y) + (v[i].z + v[i].w);
        tsum += (double)s;
    }
#pragma unroll
    for (int off = 32; off > 0; off >>= 1)
        tsum += __shfl_xor(tsum, off, 64);

    __shared__ double wsum[BLOCK / 64];
    if (lane == 0) wsum[wave] = tsum;
    __syncthreads();

    double total = 0.0;
#pragma unroll
    for (int w = 0; w < BLOCK / 64; ++w) total += wsum[w];

    const double meand = total * (1.0 / (double)ROWLEN);
    const float  meanf = (float)meand;

    // ---- phase 2: central power sums p=2..10 ----
    double acc[NMOM];
#pragma unroll
    for (int p = 0; p < NMOM; ++p) acc[p] = 0.0;

#pragma unroll
    for (int i = 0; i < NCHUNK; ++i) {
        float part[NMOM];
#pragma unroll
        for (int p = 0; p < NMOM; ++p) part[p] = 0.0f;

        const float zs[4] = { v[i].x - meanf, v[i].y - meanf,
                              v[i].z - meanf, v[i].w - meanf };
#pragma unroll
        for (int e = 0; e < 4; ++e) {
            const float z = zs[e];
            float zp = z * z;            // p = 2
            part[0] += zp;
#pragma unroll
            for (int p = 1; p < NMOM; ++p) {
                zp *= z;                 // p = 2 + p
                part[p] += zp;
            }
        }
        // flush fp32 chunk sums into f64 accumulators (bounds cancellation error)
#pragma unroll
        for (int p = 0; p < NMOM; ++p) acc[p] += (double)part[p];
    }

    // ---- wave reduce each accumulator ----
#pragma unroll
    for (int p = 0; p < NMOM; ++p) {
#pragma unroll
        for (int off = 32; off > 0; off >>= 1)
            acc[p] += __shfl_xor(acc[p], off, 64);
    }

    __shared__ double wacc[BLOCK / 64][NMOM];
    if (lane == 0) {
#pragma unroll
        for (int p = 0; p < NMOM; ++p) wacc[wave][p] = acc[p];
    }
    __syncthreads();

    // ---- epilogue: thread 0 computes the 10 outputs ----
    if (tid == 0) {
        double sums[NMOM];
#pragma unroll
        for (int p = 0; p < NMOM; ++p) {
            double s = 0.0;
#pragma unroll
            for (int w = 0; w < BLOCK / 64; ++w) s += wacc[w][p];
            sums[p] = s;
        }

        float* o = out + (size_t)row * 10;

        // std with ddof=1, + EPS (matches reference)
        const double stdv = sqrt(sums[0] / (double)(ROWLEN - 1)) + EPSV;

        // m0: signed log of |mean|, NOT clipped
        const double mean = meand;
        const double sgn0 = (mean > 0.0) ? 1.0 : (mean < 0.0 ? -1.0 : 0.0);
        o[0] = (float)(sgn0 * log(fabs(mean) + EPSV));

        double sp = stdv;                      // std^1
        for (int p = 0; p < NMOM; ++p) {
            sp *= stdv;                        // std^(p+2)
            const double cm  = sums[p] * (1.0 / (double)ROWLEN);
            const double nrm = cm / (sp + EPSV);
            const double sg  = (nrm > 0.0) ? 1.0 : (nrm < 0.0 ? -1.0 : 0.0);
            double mj = sg * log(fabs(nrm) + EPSV);
            mj = fmin(10.0, fmax(-10.0, mj));
            o[1 + p] = (float)mj;
        }
    }
}

extern "C" void kernel_launch(void* const* d_in, const int* in_sizes, int n_in,
                              void* d_out, int out_size, void* d_ws, size_t ws_size,
                              hipStream_t stream)
{
    const float* y = (const float*)d_in[0];
    float* out = (float*)d_out;
    const int B = in_sizes[0] / ROWLEN;   // 8192 rows
    moments_kernel<<<B, BLOCK, 0, stream>>>(y, out);
}

// Round 5
// 115.676 us; speedup vs baseline: 1.4017x; 1.4017x over previous
//
#include <hip/hip_runtime.h>
#include <math.h>

#define ROWLEN 16384
#define BLOCK  256
#define NCHUNK 16             // 16 x float4 = 64 floats / thread; 256*64 = 16384
#define NWAVE  (BLOCK / 64)
#define NMOM   9              // central moments p = 2..10
#define EPSV   1e-10

// Central two-pass (numerics identical to the round-3 PASSING kernel:
// fp32 power chain, per-float4 fp32 partials flushed to f64 accumulators).
// Structural change only: 256-thread blocks (4 waves) so ~4 blocks fit per CU
// -> independently phased blocks overlap load(phase1) with compute(phase2).
__global__ __launch_bounds__(BLOCK, 4) void moments_kernel(
    const float* __restrict__ y, float* __restrict__ out)
{
    const int row  = blockIdx.x;
    const int tid  = threadIdx.x;
    const int wave = tid >> 6;
    const int lane = tid & 63;

    const float4* yrow = reinterpret_cast<const float4*>(y + (size_t)row * ROWLEN);

    // ---- single HBM read: keep the whole row in registers ----
    float4 v[NCHUNK];
#pragma unroll
    for (int i = 0; i < NCHUNK; ++i)
        v[i] = yrow[i * BLOCK + tid];

    // ---- phase 1: mean ----
    double tsum = 0.0;
#pragma unroll
    for (int i = 0; i < NCHUNK; ++i) {
        float s = (v[i].x + v[i].y) + (v[i].z + v[i].w);
        tsum += (double)s;
    }
#pragma unroll
    for (int off = 32; off > 0; off >>= 1)
        tsum += __shfl_xor(tsum, off, 64);

    __shared__ double wsum[NWAVE];
    if (lane == 0) wsum[wave] = tsum;
    __syncthreads();

    double total = 0.0;
#pragma unroll
    for (int w = 0; w < NWAVE; ++w) total += wsum[w];

    const double meand = total * (1.0 / (double)ROWLEN);
    const float  meanf = (float)meand;

    // ---- phase 2: central power sums p=2..10 ----
    double acc[NMOM];
#pragma unroll
    for (int p = 0; p < NMOM; ++p) acc[p] = 0.0;

#pragma unroll
    for (int i = 0; i < NCHUNK; ++i) {
        float part[NMOM];
#pragma unroll
        for (int p = 0; p < NMOM; ++p) part[p] = 0.0f;

        const float zs[4] = { v[i].x - meanf, v[i].y - meanf,
                              v[i].z - meanf, v[i].w - meanf };
#pragma unroll
        for (int e = 0; e < 4; ++e) {
            const float z = zs[e];
            float zp = z * z;            // p = 2
            part[0] += zp;
#pragma unroll
            for (int p = 1; p < NMOM; ++p) {
                zp *= z;                 // p = 2 + p
                part[p] += zp;
            }
        }
        // flush fp32 chunk sums into f64 accumulators (bounds cancellation error)
#pragma unroll
        for (int p = 0; p < NMOM; ++p) acc[p] += (double)part[p];
    }

    // ---- wave reduce each accumulator ----
#pragma unroll
    for (int p = 0; p < NMOM; ++p) {
#pragma unroll
        for (int off = 32; off > 0; off >>= 1)
            acc[p] += __shfl_xor(acc[p], off, 64);
    }

    __shared__ double wacc[NWAVE][NMOM];
    if (lane == 0) {
#pragma unroll
        for (int p = 0; p < NMOM; ++p) wacc[wave][p] = acc[p];
    }
    __syncthreads();

    // ---- epilogue: thread 0 computes the 10 outputs ----
    if (tid == 0) {
        double sums[NMOM];
#pragma unroll
        for (int p = 0; p < NMOM; ++p) {
            double s = 0.0;
#pragma unroll
            for (int w = 0; w < NWAVE; ++w) s += wacc[w][p];
            sums[p] = s;
        }

        float* o = out + (size_t)row * 10;

        // std with ddof=1, + EPS (matches reference)
        const double stdv = sqrt(sums[0] / (double)(ROWLEN - 1)) + EPSV;

        // m0: signed log of |mean|, NOT clipped
        const double mean = meand;
        const double sgn0 = (mean > 0.0) ? 1.0 : (mean < 0.0 ? -1.0 : 0.0);
        o[0] = (float)(sgn0 * log(fabs(mean) + EPSV));

        double sp = stdv;                      // std^1
        for (int p = 0; p < NMOM; ++p) {
            sp *= stdv;                        // std^(p+2)
            const double cm  = sums[p] * (1.0 / (double)ROWLEN);
            const double nrm = cm / (sp + EPSV);
            const double sg  = (nrm > 0.0) ? 1.0 : (nrm < 0.0 ? -1.0 : 0.0);
            double mj = sg * log(fabs(nrm) + EPSV);
            mj = fmin(10.0, fmax(-10.0, mj));
            o[1 + p] = (float)mj;
        }
    }
}

extern "C" void kernel_launch(void* const* d_in, const int* in_sizes, int n_in,
                              void* d_out, int out_size, void* d_ws, size_t ws_size,
                              hipStream_t stream)
{
    const float* y = (const float*)d_in[0];
    float* out = (float*)d_out;
    const int B = in_sizes[0] / ROWLEN;   // 8192 rows
    moments_kernel<<<B, BLOCK, 0, stream>>>(y, out);
}